// Round 14
// baseline (52.041 us; speedup 1.0000x reference)
//
#include <hip/hip_runtime.h>

#define T_TOK 65536
#define DDIM 512
#define NEXP 8
#define CAP 16384

__device__ inline float wave_sum(float v) {
#pragma unroll
  for (int m = 1; m < 64; m <<= 1) v += __shfl_xor(v, m, 64);
  return v;
}

template <int CTRL>
__device__ __forceinline__ float dppf(float v) {
  return __int_as_float(
      __builtin_amdgcn_mov_dpp(__float_as_int(v), CTRL, 0xf, 0xf, true));
}
__device__ __forceinline__ void pl32swap(float& a, float& b) {
  asm("v_permlane32_swap_b32 %0, %1" : "+v"(a), "+v"(b));
}
__device__ __forceinline__ void pl16swap(float& a, float& b) {
  asm("v_permlane16_swap_b32 %0, %1" : "+v"(a), "+v"(b));
}

// --- K0a: blocks<1024: w2s[e*H+h]=sum_d W2[e,h,d]; blocks>=1024: wT rows 0..7
// (transposed gate weights wT[e*512+d] = Wg[d*8+e]) ---
__global__ void k_w2s(const float* __restrict__ W2, const float* __restrict__ Wg,
                      float* __restrict__ w2s, float* __restrict__ wT) {
  if (blockIdx.x < 1024) {
    int w = threadIdx.x >> 6, lane = threadIdx.x & 63;
    int row = blockIdx.x * 4 + w;  // < 4096
    const float* p = W2 + (size_t)row * 512;
    float sum = 0.f;
#pragma unroll
    for (int j = 0; j < 8; ++j) sum += p[lane + j * 64];
    sum = wave_sum(sum);
    if (lane == 0) w2s[row] = sum;
  } else {
    int i = (blockIdx.x - 1024) * 256 + threadIdx.x;  // < 4096
    int e = i >> 9, d = i & 511;
    wT[i] = Wg[d * 8 + e];
  }
}

// --- K0b: wT[(8+e)*512+d] = sum_h W1[e,d,h]*w2s[e,h]; last block: beta[e] ---
__global__ void k_v_beta(const float* __restrict__ W1, const float* __restrict__ b1,
                         const float* __restrict__ b2, const float* __restrict__ w2s,
                         float* __restrict__ wT, float* __restrict__ beta) {
  int w = threadIdx.x >> 6, lane = threadIdx.x & 63;
  if (blockIdx.x < 1024) {
    int rid = blockIdx.x * 4 + w;  // rid = e*512 + d
    int e = rid >> 9, d = rid & 511;
    const float* p = W1 + (size_t)rid * 512;
    const float* q = w2s + e * 512;
    float sum = 0.f;
#pragma unroll
    for (int j = 0; j < 8; ++j) { int h = lane + j * 64; sum += p[h] * q[h]; }
    sum = wave_sum(sum);
    if (lane == 0) wT[(size_t)(8 + e) * 512 + d] = sum;
  } else {
#pragma unroll
    for (int r = 0; r < 2; ++r) {
      int e = w + r * 4;
      float sum = 0.f;
#pragma unroll
      for (int j = 0; j < 8; ++j) {
        int i = lane + j * 64;
        sum += b1[e * 512 + i] * w2s[e * 512 + i] + b2[e * 512 + i];
      }
      sum = wave_sum(sum);
      if (lane == 0) beta[e] = sum;
    }
  }
}

// --- K1: 256 tokens/block, 1024 threads (16 waves). K-SPLIT GEMV (R13-proven):
// wave parity wp owns dims [wp*256, +256); lane owns 4 dims (64 weight VGPRs).
// Each token read ONCE per wave -> 134 MB total. NEW: 8-deep register prefetch
// ring (8 outstanding b128/wave, load issued 7 procs before consumption) to
// double inflight bytes — k_dots is latency(inflight)-bound per R10/R13 A/B.
// Butterfly + tail verbatim from R13 (proven). ---
__global__ __launch_bounds__(1024, 4) void k_dots(const float* __restrict__ x,
                                                  const float* __restrict__ wT,
                                                  const float* __restrict__ beta,
                                                  float4* __restrict__ wd,
                                                  int* __restrict__ epk,
                                                  int* __restrict__ hist) {
  __shared__ float sD[2][256 * 17];  // 17 coprime 32 -> benign padding
  __shared__ int c0[8], c1[8];
  const int tid = threadIdx.x;
  const int lane = tid & 63;
  const int wave = tid >> 6;        // 0..15
  const int wp = wave & 1;          // K-half (dims wp*256 .. wp*256+255)
  const int tset = wave >> 1;       // 0..7: 32-token slice within block
  const int tbase = blockIdx.x * 256 + tset * 32;

  float4 w[16];                     // w[o] = wT[o*512 + wp*256 + 4*lane .. +4)
#pragma unroll
  for (int o = 0; o < 16; ++o)
    w[o] = *reinterpret_cast<const float4*>(wT + (size_t)o * 512 + wp * 256 + 4 * lane);

  const bool b3 = (lane & 8) != 0;   // keep-bit for ror8 stage (R6 proven)
  const bool b2l = (lane & 4) != 0;  // keep-bit for half_mirror stage (R6 proven)
  const float* xb = x + (size_t)tbase * 512 + wp * 256 + 4 * lane;

  auto proc = [&](int r, float4 x0) {
    float p[16];
#pragma unroll
    for (int o = 0; o < 16; ++o)
      p[o] = x0.x * w[o].x + x0.y * w[o].y + x0.z * w[o].z + x0.w * w[o].w;
    // === R6 16-output butterfly, verbatim ===
    // A: mask 32 (o bit3 <- lane bit5)
    float a[8];
#pragma unroll
    for (int j = 0; j < 8; ++j) {
      float u = p[j], v = p[j + 8];
      pl32swap(u, v);
      a[j] = u + v;
    }
    // B: mask 16 (o bit2 <- lane bit4)
    float b[4];
#pragma unroll
    for (int j = 0; j < 4; ++j) {
      float u = a[j], v = a[j + 4];
      pl16swap(u, v);
      b[j] = u + v;
    }
    // C: mask 8 via row_ror:8 (o bit1 <- lane bit3)
    float c[2];
#pragma unroll
    for (int j = 0; j < 2; ++j) {
      float snd = b3 ? b[j] : b[j + 2];
      float kp  = b3 ? b[j + 2] : b[j];
      c[j] = kp + dppf<0x128>(snd);  // row_ror:8 == l^8 within row
    }
    // D: mask 7 via row_half_mirror (o bit0 <- lane bit2)
    {
      float snd = b2l ? c[0] : c[1];
      float kp  = b2l ? c[1] : c[0];
      float d = kp + dppf<0x141>(snd);  // l^7
      float e = d + dppf<0x4E>(d);      // quad_perm [2,3,0,1] == l^2
      float f = e + dppf<0xB1>(e);      // quad_perm [1,0,3,2] == l^1
      if ((lane & 3) == 0)
        sD[wp][(tset * 32 + r) * 17 + (lane >> 2)] = f;
    }
  };

#define LD(T) (*reinterpret_cast<const float4*>(xb + (size_t)(T) * 512))
  float4 s0, s1, s2, s3, s4, s5, s6, s7;
  s0 = LD(0); s1 = LD(1); s2 = LD(2); s3 = LD(3);
  s4 = LD(4); s5 = LD(5); s6 = LD(6);

#pragma unroll
  for (int r = 0; r < 32; r += 8) {
    if (r + 7 < 32)  s7 = LD(r + 7);
    proc(r + 0, s0);
    if (r + 8 < 32)  s0 = LD(r + 8);
    proc(r + 1, s1);
    if (r + 9 < 32)  s1 = LD(r + 9);
    proc(r + 2, s2);
    if (r + 10 < 32) s2 = LD(r + 10);
    proc(r + 3, s3);
    if (r + 11 < 32) s3 = LD(r + 11);
    proc(r + 4, s4);
    if (r + 12 < 32) s4 = LD(r + 12);
    proc(r + 5, s5);
    if (r + 13 < 32) s5 = LD(r + 13);
    proc(r + 6, s6);
    if (r + 14 < 32) s6 = LD(r + 14);
    proc(r + 7, s7);
  }
#undef LD

  __syncthreads();  // both sD halves complete
  if (tid < 8) { c0[tid] = 0; c1[tid] = 0; }
  __syncthreads();  // zeros visible
  if (tid < 256) {  // === R7 k_top2 body (combining the two K-half partials) ===
    const int t = blockIdx.x * 256 + tid;
    float l[8], dv[8];
#pragma unroll
    for (int e = 0; e < 8; ++e) {
      l[e]  = sD[0][tid * 17 + e]     + sD[1][tid * 17 + e];
      dv[e] = sD[0][tid * 17 + 8 + e] + sD[1][tid * 17 + 8 + e];
    }
    int e1 = 0; float v1 = l[0];
#pragma unroll
    for (int e = 1; e < 8; ++e) if (l[e] > v1) { v1 = l[e]; e1 = e; }  // ties -> low idx
    int e2 = 0; float v2 = -3.4e38f;
#pragma unroll
    for (int e = 0; e < 8; ++e) if (e != e1 && l[e] > v2) { v2 = l[e]; e2 = e; }
    float wexp = expf(v2 - v1);  // renormalized top-2 softmax
    float w1 = 1.f / (1.f + wexp);
    float w2 = wexp * w1;
    float d1 = 0.f, d2 = 0.f;
#pragma unroll
    for (int e = 0; e < 8; ++e) {
      d1 = (e == e1) ? dv[e] : d1;
      d2 = (e == e2) ? dv[e] : d2;
    }
    float4 o; o.x = w1; o.y = w2; o.z = d1 + beta[e1]; o.w = d2 + beta[e2];
    wd[t] = o;
    epk[t] = e1 | (e2 << 8);
    atomicAdd(&c0[e1], 1);
    atomicAdd(&c1[e2], 1);
  }
  __syncthreads();  // counts final
  if (tid < 8) {
    hist[blockIdx.x * 8 + tid] = c0[tid];
    hist[(256 + blockIdx.x) * 8 + tid] = c1[tid];
  }
}

// --- K2: exclusive scan of 512 block-histograms (k-major order), per expert.
// (R7 version, verbatim) ---
__global__ __launch_bounds__(512) void k_scan(const int* __restrict__ hist,
                                              int* __restrict__ off) {
  __shared__ int sH[4096];
  __shared__ int sT[512];
  int tid = threadIdx.x;
#pragma unroll
  for (int i = tid; i < 4096; i += 512) sH[i] = hist[i];
  __syncthreads();
  int e = tid & 7, g = tid >> 3;  // g < 64, each scans 8 rows
  int run = 0;
#pragma unroll
  for (int i = g * 8; i < g * 8 + 8; ++i) {
    int cv = sH[i * 8 + e]; sH[i * 8 + e] = run; run += cv;
  }
  sT[tid] = run;
  __syncthreads();
  int inc = run;
#pragma unroll
  for (int st = 1; st < 64; st <<= 1) {
    int add = (g >= st) ? sT[tid - st * 8] : 0;
    __syncthreads();
    inc += add;
    sT[tid] = inc;
    __syncthreads();
  }
  int exc = inc - run;
#pragma unroll
  for (int i = g * 8; i < g * 8 + 8; ++i) sH[i * 8 + e] += exc;
  __syncthreads();
#pragma unroll
  for (int i = tid; i < 4096; i += 512) off[i] = sH[i];
}

// --- K3: stable intra-block ranks via ballots -> pos -> keep -> s[t]
// (R7 version, verbatim) ---
__global__ void k_keep(const int* __restrict__ epk, const float4* __restrict__ wd,
                       const int* __restrict__ off, float* __restrict__ s) {
  __shared__ int sC0[32], sC1[32];
  int tid = threadIdx.x, lane = tid & 63, w = tid >> 6;
  int t = blockIdx.x * 256 + tid;
  int ep = epk[t]; int e1 = ep & 255, e2 = ep >> 8;
  unsigned long long lt = (1ull << lane) - 1ull;
  int wr0 = 0, wr1 = 0;
#pragma unroll
  for (int e = 0; e < 8; ++e) {
    unsigned long long m0 = __ballot(e1 == e);
    unsigned long long m1 = __ballot(e2 == e);
    if (e == e1) wr0 = __popcll(m0 & lt);
    if (e == e2) wr1 = __popcll(m1 & lt);
    if (lane == 0) { sC0[w * 8 + e] = __popcll(m0); sC1[w * 8 + e] = __popcll(m1); }
  }
  __syncthreads();
  int woff0 = 0, woff1 = 0;
  for (int wp = 0; wp < 4; ++wp) {
    if (wp < w) { woff0 += sC0[wp * 8 + e1]; woff1 += sC1[wp * 8 + e2]; }
  }
  int b = blockIdx.x;
  int pos0 = off[b * 8 + e1] + woff0 + wr0;
  int pos1 = off[(256 + b) * 8 + e2] + woff1 + wr1;
  float4 v = wd[t];
  float sv = 0.f;
  if (pos0 < CAP) sv += v.x * v.z;
  if (pos1 < CAP) sv += v.y * v.w;
  s[t] = sv;
}

// --- K4: per-row (B=8 rows of N=8192) log_softmax (R7 version, verbatim) ---
__global__ __launch_bounds__(1024) void k_lsm(const float* __restrict__ s,
                                              float* __restrict__ out) {
  __shared__ float sRa[16], sRb[16];
  int tid = threadIdx.x, lane = tid & 63, w = tid >> 6;
  size_t base = (size_t)blockIdx.x * 8192;
  float v[8];
#pragma unroll
  for (int j = 0; j < 8; ++j) v[j] = s[base + tid + j * 1024];
  float mx = v[0];
#pragma unroll
  for (int j = 1; j < 8; ++j) mx = fmaxf(mx, v[j]);
#pragma unroll
  for (int m = 1; m < 64; m <<= 1) mx = fmaxf(mx, __shfl_xor(mx, m, 64));
  if (lane == 0) sRa[w] = mx;
  __syncthreads();
#pragma unroll
  for (int i = 0; i < 16; ++i) mx = fmaxf(mx, sRa[i]);
  float sum = 0.f;
#pragma unroll
  for (int j = 0; j < 8; ++j) sum += expf(v[j] - mx);
#pragma unroll
  for (int m = 1; m < 64; m <<= 1) sum += __shfl_xor(sum, m, 64);
  if (lane == 0) sRb[w] = sum;
  __syncthreads();
  float tot = 0.f;
#pragma unroll
  for (int i = 0; i < 16; ++i) tot += sRb[i];
  float lse = logf(tot);
#pragma unroll
  for (int j = 0; j < 8; ++j) out[base + tid + j * 1024] = v[j] - mx - lse;
}

extern "C" void kernel_launch(void* const* d_in, const int* in_sizes, int n_in,
                              void* d_out, int out_size, void* d_ws, size_t ws_size,
                              hipStream_t stream) {
  const float* x  = (const float*)d_in[0];
  const float* Wg = (const float*)d_in[1];
  const float* W1 = (const float*)d_in[2];
  const float* b1 = (const float*)d_in[3];
  const float* W2 = (const float*)d_in[4];
  const float* b2 = (const float*)d_in[5];
  float* out = (float*)d_out;
  char* ws = (char*)d_ws;

  float*  w2s  = (float*)(ws);                          // 16 KB
  float*  wT   = (float*)(ws + (16u << 10));            // 32 KB: [16][512]
  float*  beta = (float*)(ws + (48u << 10));            // 32 B
  float4* wd   = (float4*)(ws + (64u << 10));           // 1 MB
  int*    epk  = (int*)(ws + (64u << 10) + (1u << 20)); // 256 KB
  int*    hist = (int*)(ws + (64u << 10) + (1u << 20) + (256u << 10)); // 16 KB
  int*    offa = (int*)(ws + (64u << 10) + (1u << 20) + (272u << 10)); // 16 KB
  float*  s    = (float*)(ws + (64u << 10) + (1u << 20) + (288u << 10)); // 256 KB

  hipLaunchKernelGGL(k_w2s,    dim3(1040), dim3(256),  0, stream, W2, Wg, w2s, wT);
  hipLaunchKernelGGL(k_v_beta, dim3(1025), dim3(256),  0, stream, W1, b1, b2, w2s, wT, beta);
  hipLaunchKernelGGL(k_dots,   dim3(256),  dim3(1024), 0, stream, x, wT, beta, wd, epk, hist);
  hipLaunchKernelGGL(k_scan,   dim3(1),    dim3(512),  0, stream, hist, offa);
  hipLaunchKernelGGL(k_keep,   dim3(256),  dim3(256),  0, stream, epk, wd, offa, s);
  hipLaunchKernelGGL(k_lsm,    dim3(8),    dim3(1024), 0, stream, s, out);
}

// Round 15
// 45.955 us; speedup vs baseline: 1.1324x; 1.1324x over previous
//
#include <hip/hip_runtime.h>

#define T_TOK 65536
#define DDIM 512
#define NEXP 8
#define CAP 16384

__device__ inline float wave_sum(float v) {
#pragma unroll
  for (int m = 1; m < 64; m <<= 1) v += __shfl_xor(v, m, 64);
  return v;
}

template <int CTRL>
__device__ __forceinline__ float dppf(float v) {
  return __int_as_float(
      __builtin_amdgcn_mov_dpp(__float_as_int(v), CTRL, 0xf, 0xf, true));
}
__device__ __forceinline__ void pl32swap(float& a, float& b) {
  asm("v_permlane32_swap_b32 %0, %1" : "+v"(a), "+v"(b));
}
__device__ __forceinline__ void pl16swap(float& a, float& b) {
  asm("v_permlane16_swap_b32 %0, %1" : "+v"(a), "+v"(b));
}

// --- K0a: blocks<1024: w2s[e*H+h]=sum_d W2[e,h,d]; blocks>=1024: wT rows 0..7
// (transposed gate weights wT[e*512+d] = Wg[d*8+e]) ---
__global__ void k_w2s(const float* __restrict__ W2, const float* __restrict__ Wg,
                      float* __restrict__ w2s, float* __restrict__ wT) {
  if (blockIdx.x < 1024) {
    int w = threadIdx.x >> 6, lane = threadIdx.x & 63;
    int row = blockIdx.x * 4 + w;  // < 4096
    const float* p = W2 + (size_t)row * 512;
    float sum = 0.f;
#pragma unroll
    for (int j = 0; j < 8; ++j) sum += p[lane + j * 64];
    sum = wave_sum(sum);
    if (lane == 0) w2s[row] = sum;
  } else {
    int i = (blockIdx.x - 1024) * 256 + threadIdx.x;  // < 4096
    int e = i >> 9, d = i & 511;
    wT[i] = Wg[d * 8 + e];
  }
}

// --- K0b: wT[(8+e)*512+d] = sum_h W1[e,d,h]*w2s[e,h]; last block: beta[e] ---
__global__ void k_v_beta(const float* __restrict__ W1, const float* __restrict__ b1,
                         const float* __restrict__ b2, const float* __restrict__ w2s,
                         float* __restrict__ wT, float* __restrict__ beta) {
  int w = threadIdx.x >> 6, lane = threadIdx.x & 63;
  if (blockIdx.x < 1024) {
    int rid = blockIdx.x * 4 + w;  // rid = e*512 + d
    int e = rid >> 9, d = rid & 511;
    const float* p = W1 + (size_t)rid * 512;
    const float* q = w2s + e * 512;
    float sum = 0.f;
#pragma unroll
    for (int j = 0; j < 8; ++j) { int h = lane + j * 64; sum += p[h] * q[h]; }
    sum = wave_sum(sum);
    if (lane == 0) wT[(size_t)(8 + e) * 512 + d] = sum;
  } else {
#pragma unroll
    for (int r = 0; r < 2; ++r) {
      int e = w + r * 4;
      float sum = 0.f;
#pragma unroll
      for (int j = 0; j < 8; ++j) {
        int i = lane + j * 64;
        sum += b1[e * 512 + i] * w2s[e * 512 + i] + b2[e * 512 + i];
      }
      sum = wave_sum(sum);
      if (lane == 0) beta[e] = sum;
    }
  }
}

// --- K1: 256 tokens/block, 1024 threads (16 waves). GEMV: wave parity wo owns
// 8 outputs in VGPRs; wave pair streams 32 tokens (4-slot register prefetch).
// Dots land in LDS sD[256][17]. Tail = R7 k_top2 body verbatim (tid<256);
// writes wd, epk, per-block c0/c1 histograms. (R10-proven, unchanged) ---
__global__ __launch_bounds__(1024, 4) void k_dots(const float* __restrict__ x,
                                                  const float* __restrict__ wT,
                                                  const float* __restrict__ beta,
                                                  float4* __restrict__ wd,
                                                  int* __restrict__ epk,
                                                  int* __restrict__ hist) {
  __shared__ float sD[256 * 17];  // 17 coprime 32 -> benign padding
  __shared__ int c0[8], c1[8];
  const int tid = threadIdx.x;
  const int lane = tid & 63;
  const int wave = tid >> 6;        // 0..15
  const int wo = wave & 1;          // output group (0: logits, 1: x·v)
  const int tset = wave >> 1;       // 0..7: 32-token slice within block
  const int tbase = blockIdx.x * 256 + tset * 32;

  float w[8][8];
#pragma unroll
  for (int o = 0; o < 8; ++o) {
    const float* wp = wT + (size_t)(wo * 8 + o) * 512 + 8 * lane;
    float4 wa = *reinterpret_cast<const float4*>(wp);
    float4 wb = *reinterpret_cast<const float4*>(wp + 4);
    w[o][0] = wa.x; w[o][1] = wa.y; w[o][2] = wa.z; w[o][3] = wa.w;
    w[o][4] = wb.x; w[o][5] = wb.y; w[o][6] = wb.z; w[o][7] = wb.w;
  }

  const bool kb3 = (lane & 8) != 0;
  const float* xb = x + (size_t)tbase * 512 + 8 * lane;

  auto proc = [&](int r, float4 x0, float4 x1) {
    float p[8];
#pragma unroll
    for (int o = 0; o < 8; ++o)
      p[o] = x0.x * w[o][0] + x0.y * w[o][1] + x0.z * w[o][2] + x0.w * w[o][3] +
             x1.x * w[o][4] + x1.y * w[o][5] + x1.z * w[o][6] + x1.w * w[o][7];
    float a[4];
#pragma unroll
    for (int j = 0; j < 4; ++j) {
      float u = p[j], v = p[j + 4];
      pl32swap(u, v);
      a[j] = u + v;
    }
    float b[2];
#pragma unroll
    for (int j = 0; j < 2; ++j) {
      float u = a[j], v = a[j + 2];
      pl16swap(u, v);
      b[j] = u + v;
    }
    float snd = kb3 ? b[0] : b[1];
    float kp  = kb3 ? b[1] : b[0];
    float c = kp + dppf<0x128>(snd);
    c += dppf<0x141>(c);  // row_half_mirror: l^7
    c += dppf<0x4E>(c);   // quad_perm [2,3,0,1]: l^2
    c += dppf<0xB1>(c);   // quad_perm [1,0,3,2]: l^1
    if ((lane & 7) == 0)
      sD[(tset * 32 + r) * 17 + wo * 8 + (lane >> 3)] = c;
  };

  float4 s00, s01, s10, s11, s20, s21, s30, s31;
  const float* q;
  q = xb;        s00 = *reinterpret_cast<const float4*>(q); s01 = *reinterpret_cast<const float4*>(q + 4);
  q = xb + 512;  s10 = *reinterpret_cast<const float4*>(q); s11 = *reinterpret_cast<const float4*>(q + 4);
  q = xb + 1024; s20 = *reinterpret_cast<const float4*>(q); s21 = *reinterpret_cast<const float4*>(q + 4);

#pragma unroll
  for (int r = 0; r < 32; r += 4) {
    q = xb + (size_t)(r + 3) * 512;
    s30 = *reinterpret_cast<const float4*>(q); s31 = *reinterpret_cast<const float4*>(q + 4);
    proc(r, s00, s01);
    if (r + 4 < 32) {
      q = xb + (size_t)(r + 4) * 512;
      s00 = *reinterpret_cast<const float4*>(q); s01 = *reinterpret_cast<const float4*>(q + 4);
    }
    proc(r + 1, s10, s11);
    if (r + 5 < 32) {
      q = xb + (size_t)(r + 5) * 512;
      s10 = *reinterpret_cast<const float4*>(q); s11 = *reinterpret_cast<const float4*>(q + 4);
    }
    proc(r + 2, s20, s21);
    if (r + 6 < 32) {
      q = xb + (size_t)(r + 6) * 512;
      s20 = *reinterpret_cast<const float4*>(q); s21 = *reinterpret_cast<const float4*>(q + 4);
    }
    proc(r + 3, s30, s31);
  }

  __syncthreads();  // sD complete
  if (tid < 8) { c0[tid] = 0; c1[tid] = 0; }
  __syncthreads();  // zeros visible
  if (tid < 256) {  // === R7 k_top2 body, dots[] -> sD ===
    const int t = blockIdx.x * 256 + tid;
    float l[8], dv[8];
#pragma unroll
    for (int e = 0; e < 8; ++e) { l[e] = sD[tid * 17 + e]; dv[e] = sD[tid * 17 + 8 + e]; }
    int e1 = 0; float v1 = l[0];
#pragma unroll
    for (int e = 1; e < 8; ++e) if (l[e] > v1) { v1 = l[e]; e1 = e; }  // ties -> low idx
    int e2 = 0; float v2 = -3.4e38f;
#pragma unroll
    for (int e = 0; e < 8; ++e) if (e != e1 && l[e] > v2) { v2 = l[e]; e2 = e; }
    float wexp = expf(v2 - v1);  // renormalized top-2 softmax
    float w1 = 1.f / (1.f + wexp);
    float w2 = wexp * w1;
    float d1 = 0.f, d2 = 0.f;
#pragma unroll
    for (int e = 0; e < 8; ++e) {
      d1 = (e == e1) ? dv[e] : d1;
      d2 = (e == e2) ? dv[e] : d2;
    }
    float4 o; o.x = w1; o.y = w2; o.z = d1 + beta[e1]; o.w = d2 + beta[e2];
    wd[t] = o;
    epk[t] = e1 | (e2 << 8);
    atomicAdd(&c0[e1], 1);
    atomicAdd(&c1[e2], 1);
  }
  __syncthreads();  // counts final
  if (tid < 8) {
    hist[blockIdx.x * 8 + tid] = c0[tid];
    hist[(256 + blockIdx.x) * 8 + tid] = c1[tid];
  }
}

// --- K2 (fused scan+keep): 256 blocks x 256 threads. Phase A: block b
// redundantly computes the only two prefix rows it needs from hist (k-major,
// 512 rows x 8 experts, L2-broadcast):
//   off0[e] = sum_{i<b} hist[i][e]
//   off1[e] = sum_{i<256} hist[i][e] + sum_{i<b} hist[256+i][e]
// Phase B: R7 k_keep ballot body verbatim, off[] -> sOff. ---
__global__ __launch_bounds__(256) void k_keep(const int* __restrict__ hist,
                                              const int* __restrict__ epk,
                                              const float4* __restrict__ wd,
                                              float* __restrict__ s) {
  __shared__ int sA[256], sB[256];
  __shared__ int sOff0[8], sOff1[8];
  __shared__ int sC0[32], sC1[32];
  const int tid = threadIdx.x;
  const int b = blockIdx.x;

  // Phase A: thread (e = tid&7, c = tid>>3) sums rows [c*8, c*8+8)
  {
    int e = tid & 7, c = tid >> 3;
    int v0 = 0, v1 = 0;
#pragma unroll
    for (int j = 0; j < 8; ++j) {
      int row = c * 8 + j;                 // 0..255
      int h0 = hist[row * 8 + e];          // k=0 rows
      int h1 = hist[(256 + row) * 8 + e];  // k=1 rows
      if (row < b) v0 += h0;
      v1 += h0;
      if (row < b) v1 += h1;
    }
    sA[c * 8 + e] = v0;
    sB[c * 8 + e] = v1;
  }
  __syncthreads();
  if (tid < 8) {  // e = tid: combine 32 chunk-partials
    int t0 = 0, t1 = 0;
#pragma unroll
    for (int c = 0; c < 32; ++c) { t0 += sA[c * 8 + tid]; t1 += sB[c * 8 + tid]; }
    sOff0[tid] = t0;
    sOff1[tid] = t1;
  }
  __syncthreads();

  // Phase B: R7 k_keep body (off[b*8+e1] -> sOff0[e1]; off[(256+b)*8+e2] -> sOff1[e2])
  int lane = tid & 63, w = tid >> 6;
  int t = b * 256 + tid;
  int ep = epk[t]; int e1 = ep & 255, e2 = ep >> 8;
  unsigned long long lt = (1ull << lane) - 1ull;
  int wr0 = 0, wr1 = 0;
#pragma unroll
  for (int e = 0; e < 8; ++e) {
    unsigned long long m0 = __ballot(e1 == e);
    unsigned long long m1 = __ballot(e2 == e);
    if (e == e1) wr0 = __popcll(m0 & lt);
    if (e == e2) wr1 = __popcll(m1 & lt);
    if (lane == 0) { sC0[w * 8 + e] = __popcll(m0); sC1[w * 8 + e] = __popcll(m1); }
  }
  __syncthreads();
  int woff0 = 0, woff1 = 0;
  for (int wp = 0; wp < 4; ++wp) {
    if (wp < w) { woff0 += sC0[wp * 8 + e1]; woff1 += sC1[wp * 8 + e2]; }
  }
  int pos0 = sOff0[e1] + woff0 + wr0;
  int pos1 = sOff1[e2] + woff1 + wr1;
  float4 v = wd[t];
  float sv = 0.f;
  if (pos0 < CAP) sv += v.x * v.z;
  if (pos1 < CAP) sv += v.y * v.w;
  s[t] = sv;
}

// --- K3: per-row (B=8 rows of N=8192) log_softmax (R7 version, verbatim) ---
__global__ __launch_bounds__(1024) void k_lsm(const float* __restrict__ s,
                                              float* __restrict__ out) {
  __shared__ float sRa[16], sRb[16];
  int tid = threadIdx.x, lane = tid & 63, w = tid >> 6;
  size_t base = (size_t)blockIdx.x * 8192;
  float v[8];
#pragma unroll
  for (int j = 0; j < 8; ++j) v[j] = s[base + tid + j * 1024];
  float mx = v[0];
#pragma unroll
  for (int j = 1; j < 8; ++j) mx = fmaxf(mx, v[j]);
#pragma unroll
  for (int m = 1; m < 64; m <<= 1) mx = fmaxf(mx, __shfl_xor(mx, m, 64));
  if (lane == 0) sRa[w] = mx;
  __syncthreads();
#pragma unroll
  for (int i = 0; i < 16; ++i) mx = fmaxf(mx, sRa[i]);
  float sum = 0.f;
#pragma unroll
  for (int j = 0; j < 8; ++j) sum += expf(v[j] - mx);
#pragma unroll
  for (int m = 1; m < 64; m <<= 1) sum += __shfl_xor(sum, m, 64);
  if (lane == 0) sRb[w] = sum;
  __syncthreads();
  float tot = 0.f;
#pragma unroll
  for (int i = 0; i < 16; ++i) tot += sRb[i];
  float lse = logf(tot);
#pragma unroll
  for (int j = 0; j < 8; ++j) out[base + tid + j * 1024] = v[j] - mx - lse;
}

extern "C" void kernel_launch(void* const* d_in, const int* in_sizes, int n_in,
                              void* d_out, int out_size, void* d_ws, size_t ws_size,
                              hipStream_t stream) {
  const float* x  = (const float*)d_in[0];
  const float* Wg = (const float*)d_in[1];
  const float* W1 = (const float*)d_in[2];
  const float* b1 = (const float*)d_in[3];
  const float* W2 = (const float*)d_in[4];
  const float* b2 = (const float*)d_in[5];
  float* out = (float*)d_out;
  char* ws = (char*)d_ws;

  float*  w2s  = (float*)(ws);                          // 16 KB
  float*  wT   = (float*)(ws + (16u << 10));            // 32 KB: [16][512]
  float*  beta = (float*)(ws + (48u << 10));            // 32 B
  float4* wd   = (float4*)(ws + (64u << 10));           // 1 MB
  int*    epk  = (int*)(ws + (64u << 10) + (1u << 20)); // 256 KB
  int*    hist = (int*)(ws + (64u << 10) + (1u << 20) + (256u << 10)); // 16 KB
  float*  s    = (float*)(ws + (64u << 10) + (1u << 20) + (288u << 10)); // 256 KB

  hipLaunchKernelGGL(k_w2s,    dim3(1040), dim3(256),  0, stream, W2, Wg, w2s, wT);
  hipLaunchKernelGGL(k_v_beta, dim3(1025), dim3(256),  0, stream, W1, b1, b2, w2s, wT, beta);
  hipLaunchKernelGGL(k_dots,   dim3(256),  dim3(1024), 0, stream, x, wT, beta, wd, epk, hist);
  hipLaunchKernelGGL(k_keep,   dim3(256),  dim3(256),  0, stream, hist, epk, wd, s);
  hipLaunchKernelGGL(k_lsm,    dim3(8),    dim3(1024), 0, stream, s, out);
}